// Round 1
// baseline (1332.387 us; speedup 1.0000x reference)
//
#include <hip/hip_runtime.h>

#define N_NODE 50000
#define N_EDGE 400000
#define INF    128

// segment tiling (32 rows/tile), boundaries are compile-time: 10000 / 20000 / 50000
#define TILES0 313
#define TILES1 313
#define TILES2 938
#define NTILES 1564

__device__ __forceinline__ void seg_decode(int b, int& ty, int& base, int& nrows) {
  if (b < TILES0)            { ty = 0; base = b * 32;                      nrows = 10000 - base; }
  else if (b < TILES0+TILES1){ ty = 1; base = 10000 + (b - TILES0) * 32;   nrows = 20000 - base; }
  else                       { ty = 2; base = 20000 + (b - TILES0-TILES1)*32; nrows = 50000 - base; }
  if (nrows > 32) nrows = 32;
}

// ---- concat features into x (= d_out) ------------------------------------
__global__ __launch_bounds__(256) void k_concat(const float* __restrict__ dr,
                                                const float* __restrict__ di,
                                                const float* __restrict__ pr,
                                                float* __restrict__ x) {
  int i = blockIdx.x * 256 + threadIdx.x;      // float4 index
  if (i >= N_NODE * 32) return;
  int row = i >> 5;
  float4 val;
  if (row < 10000)      val = ((const float4*)dr)[i];
  else if (row < 20000) val = ((const float4*)di)[i - 10000*32];
  else                  val = ((const float4*)pr)[i - 20000*32];
  ((float4*)x)[i] = val;
}

// ---- CSR build -----------------------------------------------------------
__global__ __launch_bounds__(256) void k_count(const int* __restrict__ dst, int* __restrict__ deg) {
  int e = blockIdx.x * 256 + threadIdx.x;
  if (e < N_EDGE) atomicAdd(&deg[dst[e]], 1);
}

__global__ __launch_bounds__(1024) void k_scan(const int* __restrict__ deg,
                                               int* __restrict__ off, int* __restrict__ cur) {
  __shared__ int part[1024];
  int t = threadIdx.x;
  int c0 = t * 49;
  int c1 = c0 + 49; if (c1 > N_NODE) c1 = N_NODE;
  int s = 0;
  for (int i = c0; i < c1; ++i) s += deg[i];
  part[t] = s;
  __syncthreads();
  for (int ofs = 1; ofs < 1024; ofs <<= 1) {
    int v = (t >= ofs) ? part[t - ofs] : 0;
    __syncthreads();
    part[t] += v;
    __syncthreads();
  }
  int run = (t == 0) ? 0 : part[t - 1];
  for (int i = c0; i < c1; ++i) { off[i] = run; cur[i] = run; run += deg[i]; }
  if (t == 1023) off[N_NODE] = part[1023];
}

__global__ __launch_bounds__(256) void k_fill(const int* __restrict__ dst,
                                              int* __restrict__ cur, int* __restrict__ eidx) {
  int e = blockIdx.x * 256 + threadIdx.x;
  if (e < N_EDGE) { int p = atomicAdd(&cur[dst[e]], 1); eidx[p] = e; }
}

// ---- typed K/Q/V projection ---------------------------------------------
__global__ __launch_bounds__(256) void k_qkv(const float* __restrict__ x,
                                             const float* __restrict__ Wk,
                                             const float* __restrict__ Wq,
                                             const float* __restrict__ Wv,
                                             float* __restrict__ kb,
                                             float* __restrict__ qb,
                                             float* __restrict__ vb) {
  __shared__ float xs[32][128];
  int ty, base, nrows;
  seg_decode(blockIdx.x, ty, base, nrows);
  int t = threadIdx.x;
#pragma unroll
  for (int it = 0; it < 4; ++it) {
    int idx4 = t + it * 256;
    int row = idx4 >> 5, c4 = idx4 & 31;
    float4 val = make_float4(0.f, 0.f, 0.f, 0.f);
    if (row < nrows) val = ((const float4*)(x + (size_t)(base + row) * INF))[c4];
    ((float4*)&xs[row][0])[c4] = val;
  }
  __syncthreads();
  int o = t & 127, g = t >> 7;
  float ak[16], aq[16], av[16];
#pragma unroll
  for (int j = 0; j < 16; ++j) { ak[j] = 0.f; aq[j] = 0.f; av[j] = 0.f; }
  const float* WK = Wk + ty * 16384;
  const float* WQ = Wq + ty * 16384;
  const float* WV = Wv + ty * 16384;
  for (int i0 = 0; i0 < 32; ++i0) {
    float wk[4], wq[4], wv[4];
#pragma unroll
    for (int di = 0; di < 4; ++di) {
      int i = i0 * 4 + di;
      wk[di] = WK[i * 128 + o];
      wq[di] = WQ[i * 128 + o];
      wv[di] = WV[i * 128 + o];
    }
#pragma unroll
    for (int j = 0; j < 16; ++j) {
      float4 x4 = ((const float4*)&xs[g * 16 + j][0])[i0];
      ak[j] += x4.x * wk[0] + x4.y * wk[1] + x4.z * wk[2] + x4.w * wk[3];
      aq[j] += x4.x * wq[0] + x4.y * wq[1] + x4.z * wq[2] + x4.w * wq[3];
      av[j] += x4.x * wv[0] + x4.y * wv[1] + x4.z * wv[2] + x4.w * wv[3];
    }
  }
#pragma unroll
  for (int j = 0; j < 16; ++j) {
    int row = g * 16 + j;
    if (row < nrows) {
      size_t p = (size_t)(base + row) * INF + o;
      kb[p] = ak[j]; qb[p] = aq[j]; vb[p] = av[j];
    }
  }
}

// ---- per-edge attention logits ------------------------------------------
// 16-lane group per (edge, head); 32 edges per block (amortize 32KB rel_att LDS preload)
__global__ __launch_bounds__(256) void k_logits(const float* __restrict__ kb,
                                                const float* __restrict__ qb,
                                                const int* __restrict__ src,
                                                const int* __restrict__ dst,
                                                const int* __restrict__ etp,
                                                const float* __restrict__ rel_att,
                                                const float* __restrict__ pri,
                                                float* __restrict__ a) {
  __shared__ float ra[8192];   // [h][et][dp][d] flat, 32 KB
  int t = threadIdx.x;
#pragma unroll
  for (int it = 0; it < 32; ++it) ra[t + it * 256] = rel_att[t + it * 256];
  __syncthreads();
  int grp = t >> 4, lane = t & 15;
  int h = grp & 7;
  for (int it = 0; it < 16; ++it) {
    int e = blockIdx.x * 32 + it * 2 + (grp >> 3);
    if (e >= N_EDGE) return;
    int s = src[e], dd = dst[e], ty = etp[e];
    float ki = kb[(size_t)s * INF + h * 16 + lane];
    float qd = qb[(size_t)dd * INF + h * 16 + lane];
    const float* rb = ra + (h * 4 + ty) * 256;
    float kw = 0.f;
#pragma unroll
    for (int i = 0; i < 16; ++i)
      kw += __shfl(ki, i, 16) * rb[i * 16 + lane];
    float p = kw * qd;
    p += __shfl_xor(p, 1, 16);
    p += __shfl_xor(p, 2, 16);
    p += __shfl_xor(p, 4, 16);
    p += __shfl_xor(p, 8, 16);
    if (lane == 0) a[(size_t)e * 8 + h] = p * pri[h * 4 + ty] * 0.25f;
  }
}

// ---- per-dst-node edge softmax (no atomics; writes ea in place + esum) ---
__global__ __launch_bounds__(64) void k_softmax(const int* __restrict__ off,
                                                const int* __restrict__ eidx,
                                                float* __restrict__ a,
                                                float* __restrict__ esum) {
  int n = blockIdx.x;
  int lane = threadIdx.x;
  int h = lane & 7, slot = lane >> 3;
  int o0 = off[n], o1 = off[n + 1];
  float m = -1e30f;
  for (int b = o0; b < o1; b += 8) {
    int p = b + slot;
    if (p < o1) { int e = eidx[p]; m = fmaxf(m, a[(size_t)e * 8 + h]); }
  }
  m = fmaxf(m, __shfl_xor(m, 8));
  m = fmaxf(m, __shfl_xor(m, 16));
  m = fmaxf(m, __shfl_xor(m, 32));
  float s = 0.f;
  for (int b = o0; b < o1; b += 8) {
    int p = b + slot;
    if (p < o1) {
      int e = eidx[p];
      float ea = __expf(a[(size_t)e * 8 + h] - m);
      a[(size_t)e * 8 + h] = ea;
      s += ea;
    }
  }
  s += __shfl_xor(s, 8);
  s += __shfl_xor(s, 16);
  s += __shfl_xor(s, 32);
  if (lane < 8) esum[(size_t)n * 8 + lane] = s;
}

// ---- per-dst-node message aggregation (no atomics) -----------------------
// one wave per node; lane = (hq 0..3) * 16 + d; each lane handles heads hq and hq+4
__global__ __launch_bounds__(64) void k_agg(const float* __restrict__ vb,
                                            const float* __restrict__ ea,
                                            const float* __restrict__ esum,
                                            const int* __restrict__ off,
                                            const int* __restrict__ eidx,
                                            const int* __restrict__ src,
                                            const int* __restrict__ etp,
                                            const float* __restrict__ rel_msg,
                                            float* __restrict__ hb) {
  int n = blockIdx.x;
  int lane = threadIdx.x;
  int d = lane & 15, hq = lane >> 4;
  int o0 = off[n], o1 = off[n + 1];
  float es0 = esum[(size_t)n * 8 + hq];
  float es1 = esum[(size_t)n * 8 + hq + 4];
  float inv0 = es0 > 0.f ? 1.f / es0 : 0.f;
  float inv1 = es1 > 0.f ? 1.f / es1 : 0.f;
  float acc0 = 0.f, acc1 = 0.f;
  for (int p = o0; p < o1; ++p) {
    int e = eidx[p];
    int s = src[e], ty = etp[e];
    float v0 = vb[(size_t)s * INF + lane];
    float v1 = vb[(size_t)s * INF + 64 + lane];
    float at0 = ea[(size_t)e * 8 + hq] * inv0;
    float at1 = ea[(size_t)e * 8 + hq + 4] * inv1;
    const float* rm0 = rel_msg + ((hq * 4 + ty) * 16) * 16;
    const float* rm1 = rel_msg + (((hq + 4) * 4 + ty) * 16) * 16;
    float mw0 = 0.f, mw1 = 0.f;
#pragma unroll
    for (int i = 0; i < 16; ++i) {
      float vv0 = __shfl(v0, hq * 16 + i, 64);
      float vv1 = __shfl(v1, hq * 16 + i, 64);
      mw0 += vv0 * rm0[i * 16 + d];
      mw1 += vv1 * rm1[i * 16 + d];
    }
    acc0 += at0 * mw0;
    acc1 += at1 * mw1;
  }
  hb[(size_t)n * INF + hq * 16 + d] = acc0;
  hb[(size_t)n * INF + (hq + 4) * 16 + d] = acc1;
}

// ---- typed output projection + sigmoid-skip residual (in-place on x) -----
__global__ __launch_bounds__(256) void k_out(const float* __restrict__ hb,
                                             const float* __restrict__ Wa,
                                             const float* __restrict__ skipv,
                                             float* __restrict__ xio) {
  __shared__ float hs[32][128];
  int ty, base, nrows;
  seg_decode(blockIdx.x, ty, base, nrows);
  int t = threadIdx.x;
#pragma unroll
  for (int it = 0; it < 4; ++it) {
    int idx4 = t + it * 256;
    int row = idx4 >> 5, c4 = idx4 & 31;
    float4 val = make_float4(0.f, 0.f, 0.f, 0.f);
    if (row < nrows) val = ((const float4*)(hb + (size_t)(base + row) * INF))[c4];
    ((float4*)&hs[row][0])[c4] = val;
  }
  __syncthreads();
  int o = t & 127, g = t >> 7;
  float acc[16];
#pragma unroll
  for (int j = 0; j < 16; ++j) acc[j] = 0.f;
  const float* WA = Wa + ty * 16384;
  for (int i0 = 0; i0 < 32; ++i0) {
    float wa[4];
#pragma unroll
    for (int di = 0; di < 4; ++di) wa[di] = WA[(i0 * 4 + di) * 128 + o];
#pragma unroll
    for (int j = 0; j < 16; ++j) {
      float4 h4 = ((const float4*)&hs[g * 16 + j][0])[i0];
      acc[j] += h4.x * wa[0] + h4.y * wa[1] + h4.z * wa[2] + h4.w * wa[3];
    }
  }
  float alpha = 1.f / (1.f + __expf(-skipv[ty]));
  float beta = 1.f - alpha;
#pragma unroll
  for (int j = 0; j < 16; ++j) {
    int row = g * 16 + j;
    if (row < nrows) {
      size_t p = (size_t)(base + row) * INF + o;
      xio[p] = acc[j] * alpha + xio[p] * beta;
    }
  }
}

extern "C" void kernel_launch(void* const* d_in, const int* in_sizes, int n_in,
                              void* d_out, int out_size, void* d_ws, size_t ws_size,
                              hipStream_t stream) {
  const float* drug = (const float*)d_in[0];
  const float* dis  = (const float*)d_in[1];
  const float* prot = (const float*)d_in[2];
  const int* src    = (const int*)d_in[3];
  const int* dst    = (const int*)d_in[4];
  const int* etp    = (const int*)d_in[5];
  const float* Wk   = (const float*)d_in[6];
  const float* Wq   = (const float*)d_in[7];
  const float* Wv   = (const float*)d_in[8];
  const float* Wa   = (const float*)d_in[9];
  const float* rel_att = (const float*)d_in[10];
  const float* rel_msg = (const float*)d_in[11];
  const float* pri  = (const float*)d_in[12];
  const float* skip = (const float*)d_in[13];
  float* x = (float*)d_out;

  char* w = (char*)d_ws;
  float* kb   = (float*)(w + 0);            // 25,600,000 B
  float* qb   = (float*)(w + 25600000);     // 25,600,000 B
  float* vb   = (float*)(w + 51200000);     // 25,600,000 B
  float* hb   = (float*)(w + 76800000);     // 25,600,000 B
  float* ab   = (float*)(w + 102400000);    // 12,800,000 B (logits -> ea in place)
  float* esum = (float*)(w + 115200000);    //  1,600,000 B
  int*   deg  = (int*)(w + 116800000);      //    200,000 B
  int*   off  = (int*)(w + 117000064);      //    200,004 B
  int*   cur  = (int*)(w + 117200128);      //    200,000 B
  int*   eidx = (int*)(w + 117400192);      //  1,600,000 B

  // x = concat(features)
  k_concat<<<6250, 256, 0, stream>>>(drug, dis, prot, x);

  // CSR by dst (edges constant across layers)
  hipMemsetAsync(deg, 0, N_NODE * sizeof(int), stream);
  k_count<<<(N_EDGE + 255) / 256, 256, 0, stream>>>(dst, deg);
  k_scan<<<1, 1024, 0, stream>>>(deg, off, cur);
  k_fill<<<(N_EDGE + 255) / 256, 256, 0, stream>>>(dst, cur, eidx);

  for (int layer = 0; layer < 2; ++layer) {
    k_qkv<<<NTILES, 256, 0, stream>>>(x, Wk, Wq, Wv, kb, qb, vb);
    k_logits<<<N_EDGE / 32, 256, 0, stream>>>(kb, qb, src, dst, etp, rel_att, pri, ab);
    k_softmax<<<N_NODE, 64, 0, stream>>>(off, eidx, ab, esum);
    k_agg<<<N_NODE, 64, 0, stream>>>(vb, ab, esum, off, eidx, src, etp, rel_msg, hb);
    k_out<<<NTILES, 256, 0, stream>>>(hb, Wa, skip, x);
  }
}

// Round 2
// 1297.978 us; speedup vs baseline: 1.0265x; 1.0265x over previous
//
#include <hip/hip_runtime.h>

#define N_NODE 50000
#define N_EDGE 400000
#define INF    128

// segment tiling (32 rows/tile), boundaries are compile-time: 10000 / 20000 / 50000
#define TILES0 313
#define TILES1 313
#define TILES2 938
#define NTILES 1564

__device__ __forceinline__ void seg_decode(int b, int& ty, int& base, int& nrows) {
  if (b < TILES0)            { ty = 0; base = b * 32;                      nrows = 10000 - base; }
  else if (b < TILES0+TILES1){ ty = 1; base = 10000 + (b - TILES0) * 32;   nrows = 20000 - base; }
  else                       { ty = 2; base = 20000 + (b - TILES0-TILES1)*32; nrows = 50000 - base; }
  if (nrows > 32) nrows = 32;
}

// ---- concat features into x (= d_out) ------------------------------------
__global__ __launch_bounds__(256) void k_concat(const float* __restrict__ dr,
                                                const float* __restrict__ di,
                                                const float* __restrict__ pr,
                                                float* __restrict__ x) {
  int i = blockIdx.x * 256 + threadIdx.x;      // float4 index
  if (i >= N_NODE * 32) return;
  int row = i >> 5;
  float4 val;
  if (row < 10000)      val = ((const float4*)dr)[i];
  else if (row < 20000) val = ((const float4*)di)[i - 10000*32];
  else                  val = ((const float4*)pr)[i - 20000*32];
  ((float4*)x)[i] = val;
}

// ---- CSR build -----------------------------------------------------------
__global__ __launch_bounds__(256) void k_count(const int* __restrict__ dst, int* __restrict__ deg) {
  int e = blockIdx.x * 256 + threadIdx.x;
  if (e < N_EDGE) atomicAdd(&deg[dst[e]], 1);
}

__global__ __launch_bounds__(1024) void k_scan(const int* __restrict__ deg,
                                               int* __restrict__ off, int* __restrict__ cur) {
  __shared__ int part[1024];
  int t = threadIdx.x;
  int c0 = t * 49;
  int c1 = c0 + 49; if (c1 > N_NODE) c1 = N_NODE;
  int s = 0;
  for (int i = c0; i < c1; ++i) s += deg[i];
  part[t] = s;
  __syncthreads();
  for (int ofs = 1; ofs < 1024; ofs <<= 1) {
    int v = (t >= ofs) ? part[t - ofs] : 0;
    __syncthreads();
    part[t] += v;
    __syncthreads();
  }
  int run = (t == 0) ? 0 : part[t - 1];
  for (int i = c0; i < c1; ++i) { off[i] = run; cur[i] = run; run += deg[i]; }
  if (t == 1023) off[N_NODE] = part[1023];
}

__global__ __launch_bounds__(256) void k_fill(const int* __restrict__ dst,
                                              int* __restrict__ cur, int* __restrict__ eidx) {
  int e = blockIdx.x * 256 + threadIdx.x;
  if (e < N_EDGE) { int p = atomicAdd(&cur[dst[e]], 1); eidx[p] = e; }
}

// ---- transpose rel_msg: AmT[h][ty][do][di] = rel_msg[h][ty][di][do] ------
__global__ __launch_bounds__(256) void k_trmsg(const float* __restrict__ rm,
                                               float* __restrict__ AmT) {
  int i = blockIdx.x * 256 + threadIdx.x;   // 8192 total
  int di = i & 15, doo = (i >> 4) & 15, ty = (i >> 8) & 3, hh = i >> 10;
  AmT[i] = rm[((hh * 4 + ty) * 16 + di) * 16 + doo];
}

// ---- typed K/Q/V projection ---------------------------------------------
__global__ __launch_bounds__(256) void k_qkv(const float* __restrict__ x,
                                             const float* __restrict__ Wk,
                                             const float* __restrict__ Wq,
                                             const float* __restrict__ Wv,
                                             float* __restrict__ kb,
                                             float* __restrict__ qb,
                                             float* __restrict__ vb) {
  __shared__ float xs[32][128];
  int ty, base, nrows;
  seg_decode(blockIdx.x, ty, base, nrows);
  int t = threadIdx.x;
#pragma unroll
  for (int it = 0; it < 4; ++it) {
    int idx4 = t + it * 256;
    int row = idx4 >> 5, c4 = idx4 & 31;
    float4 val = make_float4(0.f, 0.f, 0.f, 0.f);
    if (row < nrows) val = ((const float4*)(x + (size_t)(base + row) * INF))[c4];
    ((float4*)&xs[row][0])[c4] = val;
  }
  __syncthreads();
  int o = t & 127, g = t >> 7;
  float ak[16], aq[16], av[16];
#pragma unroll
  for (int j = 0; j < 16; ++j) { ak[j] = 0.f; aq[j] = 0.f; av[j] = 0.f; }
  const float* WK = Wk + ty * 16384;
  const float* WQ = Wq + ty * 16384;
  const float* WV = Wv + ty * 16384;
  for (int i0 = 0; i0 < 32; ++i0) {
    float wk[4], wq[4], wv[4];
#pragma unroll
    for (int di = 0; di < 4; ++di) {
      int i = i0 * 4 + di;
      wk[di] = WK[i * 128 + o];
      wq[di] = WQ[i * 128 + o];
      wv[di] = WV[i * 128 + o];
    }
#pragma unroll
    for (int j = 0; j < 16; ++j) {
      float4 x4 = ((const float4*)&xs[g * 16 + j][0])[i0];
      ak[j] += x4.x * wk[0] + x4.y * wk[1] + x4.z * wk[2] + x4.w * wk[3];
      aq[j] += x4.x * wq[0] + x4.y * wq[1] + x4.z * wq[2] + x4.w * wq[3];
      av[j] += x4.x * wv[0] + x4.y * wv[1] + x4.z * wv[2] + x4.w * wv[3];
    }
  }
#pragma unroll
  for (int j = 0; j < 16; ++j) {
    int row = g * 16 + j;
    if (row < nrows) {
      size_t p = (size_t)(base + row) * INF + o;
      kb[p] = ak[j]; qb[p] = aq[j]; vb[p] = av[j];
    }
  }
}

// ---- fused attention: logits + edge-softmax + aggregation ---------------
// 1 wave per dst node, 4 nodes per 256-thread block.
// lane l holds dims (2l, 2l+1); head h = l>>3, j = l&7 -> di0=2j, di1=2j+1.
// qA[ty] = rel_att[h,ty] . q[n] computed once per node (in regs);
// per edge: gather raw kb/vb rows (coalesced 512B), dot vs qA, online softmax,
// accumulate raw v into per-etype acc; apply rel_msg^T once at the end.
__global__ __launch_bounds__(256) void k_fused(const float* __restrict__ kb,
                                               const float* __restrict__ qb,
                                               const float* __restrict__ vb,
                                               const int* __restrict__ off,
                                               const int* __restrict__ eidx,
                                               const int* __restrict__ src,
                                               const int* __restrict__ etp,
                                               const float* __restrict__ rel_att,
                                               const float* __restrict__ AmT,
                                               const float* __restrict__ pri,
                                               float* __restrict__ hb) {
  __shared__ float qs[4][128];
  __shared__ float accs[4][4][128];
  int w = threadIdx.x >> 6, l = threadIdx.x & 63;
  int n = blockIdx.x * 4 + w;
  int h = l >> 3, j = l & 7;

  // stage q row for this wave's node
  float2 qv = ((const float2*)qb)[(size_t)n * 64 + l];
  ((float2*)&qs[w][0])[l] = qv;
  __syncthreads();

  // qA[ty][di0,di1] per lane
  float2 qa0, qa1, qa2, qa3;
#define QA_COMPUTE(QA, TY) { \
    float ax = 0.f, ay = 0.f; \
    const float4* Ar = (const float4*)(rel_att + ((h * 4 + (TY)) * 16) * 16); \
    _Pragma("unroll") \
    for (int d4 = 0; d4 < 4; ++d4) { \
      float4 q4 = *((float4*)&qs[w][h * 16 + d4 * 4]); \
      float4 a0 = Ar[(2 * j) * 4 + d4]; \
      float4 a1 = Ar[(2 * j + 1) * 4 + d4]; \
      ax += a0.x * q4.x + a0.y * q4.y + a0.z * q4.z + a0.w * q4.w; \
      ay += a1.x * q4.x + a1.y * q4.y + a1.z * q4.z + a1.w * q4.w; \
    } \
    QA = make_float2(ax, ay); }
  QA_COMPUTE(qa0, 0)
  QA_COMPUTE(qa1, 1)
  QA_COMPUTE(qa2, 2)
  QA_COMPUTE(qa3, 3)
#undef QA_COMPUTE

  float4 prh = ((const float4*)pri)[h];
  int o0 = off[n], o1 = off[n + 1];
  float m = -INFINITY, ssum = 0.f;
  float2 acc0 = make_float2(0.f, 0.f), acc1 = acc0, acc2 = acc0, acc3 = acc0;

  for (int p = o0; p < o1; ++p) {
    int e = eidx[p];
    int s = src[e];
    int ty = etp[e];
    float2 kv = ((const float2*)kb)[(size_t)s * 64 + l];
    float2 vv = ((const float2*)vb)[(size_t)s * 64 + l];
    float2 qat = (ty == 0) ? qa0 : (ty == 1) ? qa1 : (ty == 2) ? qa2 : qa3;
    float part = kv.x * qat.x + kv.y * qat.y;
    part += __shfl_xor(part, 1);
    part += __shfl_xor(part, 2);
    part += __shfl_xor(part, 4);
    float pr = (ty == 0) ? prh.x : (ty == 1) ? prh.y : (ty == 2) ? prh.z : prh.w;
    float a = part * pr * 0.25f;
    float mn = fmaxf(m, a);
    float sc = __expf(m - mn);
    float wgt = __expf(a - mn);
    ssum = ssum * sc + wgt;
    float w0 = (ty == 0) ? wgt : 0.f;
    float w1 = (ty == 1) ? wgt : 0.f;
    float w2 = (ty == 2) ? wgt : 0.f;
    float w3 = (ty == 3) ? wgt : 0.f;
    acc0.x = acc0.x * sc + w0 * vv.x; acc0.y = acc0.y * sc + w0 * vv.y;
    acc1.x = acc1.x * sc + w1 * vv.x; acc1.y = acc1.y * sc + w1 * vv.y;
    acc2.x = acc2.x * sc + w2 * vv.x; acc2.y = acc2.y * sc + w2 * vv.y;
    acc3.x = acc3.x * sc + w3 * vv.x; acc3.y = acc3.y * sc + w3 * vv.y;
    m = mn;
  }

  float inv = (ssum > 0.f) ? 1.f / ssum : 0.f;
  acc0.x *= inv; acc0.y *= inv;
  acc1.x *= inv; acc1.y *= inv;
  acc2.x *= inv; acc2.y *= inv;
  acc3.x *= inv; acc3.y *= inv;

  // stage normalized per-ty accumulators, then apply rel_msg^T once
  ((float2*)&accs[w][0][0])[l] = acc0;
  ((float2*)&accs[w][1][0])[l] = acc1;
  ((float2*)&accs[w][2][0])[l] = acc2;
  ((float2*)&accs[w][3][0])[l] = acc3;

  float ox = 0.f, oy = 0.f;
#pragma unroll
  for (int ty = 0; ty < 4; ++ty) {
    const float4* AmR = (const float4*)(AmT + ((h * 4 + ty) * 16) * 16);
#pragma unroll
    for (int d4 = 0; d4 < 4; ++d4) {
      float4 ac = *((float4*)&accs[w][ty][h * 16 + d4 * 4]);
      float4 m0 = AmR[(2 * j) * 4 + d4];
      float4 m1 = AmR[(2 * j + 1) * 4 + d4];
      ox += m0.x * ac.x + m0.y * ac.y + m0.z * ac.z + m0.w * ac.w;
      oy += m1.x * ac.x + m1.y * ac.y + m1.z * ac.z + m1.w * ac.w;
    }
  }
  ((float2*)hb)[(size_t)n * 64 + l] = make_float2(ox, oy);
}

// ---- typed output projection + sigmoid-skip residual (in-place on x) -----
__global__ __launch_bounds__(256) void k_out(const float* __restrict__ hb,
                                             const float* __restrict__ Wa,
                                             const float* __restrict__ skipv,
                                             float* __restrict__ xio) {
  __shared__ float hs[32][128];
  int ty, base, nrows;
  seg_decode(blockIdx.x, ty, base, nrows);
  int t = threadIdx.x;
#pragma unroll
  for (int it = 0; it < 4; ++it) {
    int idx4 = t + it * 256;
    int row = idx4 >> 5, c4 = idx4 & 31;
    float4 val = make_float4(0.f, 0.f, 0.f, 0.f);
    if (row < nrows) val = ((const float4*)(hb + (size_t)(base + row) * INF))[c4];
    ((float4*)&hs[row][0])[c4] = val;
  }
  __syncthreads();
  int o = t & 127, g = t >> 7;
  float acc[16];
#pragma unroll
  for (int j = 0; j < 16; ++j) acc[j] = 0.f;
  const float* WA = Wa + ty * 16384;
  for (int i0 = 0; i0 < 32; ++i0) {
    float wa[4];
#pragma unroll
    for (int di = 0; di < 4; ++di) wa[di] = WA[(i0 * 4 + di) * 128 + o];
#pragma unroll
    for (int j = 0; j < 16; ++j) {
      float4 h4 = ((const float4*)&hs[g * 16 + j][0])[i0];
      acc[j] += h4.x * wa[0] + h4.y * wa[1] + h4.z * wa[2] + h4.w * wa[3];
    }
  }
  float alpha = 1.f / (1.f + __expf(-skipv[ty]));
  float beta = 1.f - alpha;
#pragma unroll
  for (int j = 0; j < 16; ++j) {
    int row = g * 16 + j;
    if (row < nrows) {
      size_t p = (size_t)(base + row) * INF + o;
      xio[p] = acc[j] * alpha + xio[p] * beta;
    }
  }
}

extern "C" void kernel_launch(void* const* d_in, const int* in_sizes, int n_in,
                              void* d_out, int out_size, void* d_ws, size_t ws_size,
                              hipStream_t stream) {
  const float* drug = (const float*)d_in[0];
  const float* dis  = (const float*)d_in[1];
  const float* prot = (const float*)d_in[2];
  const int* src    = (const int*)d_in[3];
  const int* dst    = (const int*)d_in[4];
  const int* etp    = (const int*)d_in[5];
  const float* Wk   = (const float*)d_in[6];
  const float* Wq   = (const float*)d_in[7];
  const float* Wv   = (const float*)d_in[8];
  const float* Wa   = (const float*)d_in[9];
  const float* rel_att = (const float*)d_in[10];
  const float* rel_msg = (const float*)d_in[11];
  const float* pri  = (const float*)d_in[12];
  const float* skip = (const float*)d_in[13];
  float* x = (float*)d_out;

  char* w = (char*)d_ws;
  float* kb   = (float*)(w + 0);            // 25,600,000 B
  float* qb   = (float*)(w + 25600000);     // 25,600,000 B
  float* vb   = (float*)(w + 51200000);     // 25,600,000 B
  float* hb   = (float*)(w + 76800000);     // 25,600,000 B
  float* AmT  = (float*)(w + 102400000);    //     32,768 B
  int*   deg  = (int*)(w + 102432768);      //    200,000 B
  int*   off  = (int*)(w + 102632768);      //    200,004 B
  int*   cur  = (int*)(w + 102832772);      //    200,000 B
  int*   eidx = (int*)(w + 103032772);      //  1,600,000 B

  // x = concat(features)
  k_concat<<<6250, 256, 0, stream>>>(drug, dis, prot, x);

  // CSR by dst (edges constant across layers)
  hipMemsetAsync(deg, 0, N_NODE * sizeof(int), stream);
  k_count<<<(N_EDGE + 255) / 256, 256, 0, stream>>>(dst, deg);
  k_scan<<<1, 1024, 0, stream>>>(deg, off, cur);
  k_fill<<<(N_EDGE + 255) / 256, 256, 0, stream>>>(dst, cur, eidx);

  // rel_msg transpose (constant across layers)
  k_trmsg<<<32, 256, 0, stream>>>(rel_msg, AmT);

  for (int layer = 0; layer < 2; ++layer) {
    k_qkv<<<NTILES, 256, 0, stream>>>(x, Wk, Wq, Wv, kb, qb, vb);
    k_fused<<<12500, 256, 0, stream>>>(kb, qb, vb, off, eidx, src, etp,
                                       rel_att, AmT, pri, hb);
    k_out<<<NTILES, 256, 0, stream>>>(hb, Wa, skip, x);
  }
}

// Round 3
// 1204.149 us; speedup vs baseline: 1.1065x; 1.0779x over previous
//
#include <hip/hip_runtime.h>

#define N_NODE 50000
#define N_EDGE 400000
#define INF    128

// segment tiling (32 rows/tile), boundaries are compile-time: 10000 / 20000 / 50000
#define TILES0 313
#define TILES1 313
#define TILES2 938
#define NTILES 1564

__device__ __forceinline__ void seg_decode(int b, int& ty, int& base, int& nrows) {
  if (b < TILES0)            { ty = 0; base = b * 32;                      nrows = 10000 - base; }
  else if (b < TILES0+TILES1){ ty = 1; base = 10000 + (b - TILES0) * 32;   nrows = 20000 - base; }
  else                       { ty = 2; base = 20000 + (b - TILES0-TILES1)*32; nrows = 50000 - base; }
  if (nrows > 32) nrows = 32;
}

__device__ __forceinline__ float blo(unsigned u) { return __uint_as_float(u << 16); }
__device__ __forceinline__ float bhi(unsigned u) { return __uint_as_float(u & 0xffff0000u); }
// pack two f32 -> bf16x2 (RNE), lo = even dim, hi = odd dim
__device__ __forceinline__ unsigned bpack(float lo, float hi) {
  unsigned a = __float_as_uint(lo), b = __float_as_uint(hi);
  a = (a + 0x7fffu + ((a >> 16) & 1u)) >> 16;
  b = (b + 0x7fffu + ((b >> 16) & 1u)) & 0xffff0000u;
  return a | b;
}

// ---- concat features into x (= d_out) ------------------------------------
__global__ __launch_bounds__(256) void k_concat(const float* __restrict__ dr,
                                                const float* __restrict__ di,
                                                const float* __restrict__ pr,
                                                float* __restrict__ x) {
  int i = blockIdx.x * 256 + threadIdx.x;      // float4 index
  if (i >= N_NODE * 32) return;
  int row = i >> 5;
  float4 val;
  if (row < 10000)      val = ((const float4*)dr)[i];
  else if (row < 20000) val = ((const float4*)di)[i - 10000*32];
  else                  val = ((const float4*)pr)[i - 20000*32];
  ((float4*)x)[i] = val;
}

// ---- CSR build -----------------------------------------------------------
__global__ __launch_bounds__(256) void k_count(const int* __restrict__ dst, int* __restrict__ deg) {
  int e = blockIdx.x * 256 + threadIdx.x;
  if (e < N_EDGE) atomicAdd(&deg[dst[e]], 1);
}

__global__ __launch_bounds__(1024) void k_scan(const int* __restrict__ deg,
                                               int* __restrict__ off, int* __restrict__ cur) {
  __shared__ int part[1024];
  int t = threadIdx.x;
  int c0 = t * 49;
  int c1 = c0 + 49; if (c1 > N_NODE) c1 = N_NODE;
  int s = 0;
  for (int i = c0; i < c1; ++i) s += deg[i];
  part[t] = s;
  __syncthreads();
  for (int ofs = 1; ofs < 1024; ofs <<= 1) {
    int v = (t >= ofs) ? part[t - ofs] : 0;
    __syncthreads();
    part[t] += v;
    __syncthreads();
  }
  int run = (t == 0) ? 0 : part[t - 1];
  for (int i = c0; i < c1; ++i) { off[i] = run; cur[i] = run; run += deg[i]; }
  if (t == 1023) off[N_NODE] = part[1023];
}

__global__ __launch_bounds__(256) void k_fill(const int* __restrict__ dst,
                                              int* __restrict__ cur, int* __restrict__ eidx) {
  int e = blockIdx.x * 256 + threadIdx.x;
  if (e < N_EDGE) { int p = atomicAdd(&cur[dst[e]], 1); eidx[p] = e; }
}

// ---- transpose rel_msg: AmT[h][ty][do][di] = rel_msg[h][ty][di][do] ------
__global__ __launch_bounds__(256) void k_trmsg(const float* __restrict__ rm,
                                               float* __restrict__ AmT) {
  int i = blockIdx.x * 256 + threadIdx.x;   // 8192 total
  int di = i & 15, doo = (i >> 4) & 15, ty = (i >> 8) & 3, hh = i >> 10;
  AmT[i] = rm[((hh * 4 + ty) * 16 + di) * 16 + doo];
}

// ---- typed K/Q/V projection; k,v packed interleaved bf16 -----------------
// kvb[n] = 64 x uint2 : elem l = { bf16x2(k[2l],k[2l+1]), bf16x2(v[2l],v[2l+1]) }
__global__ __launch_bounds__(256) void k_qkv(const float* __restrict__ x,
                                             const float* __restrict__ Wk,
                                             const float* __restrict__ Wq,
                                             const float* __restrict__ Wv,
                                             uint2* __restrict__ kvb,
                                             float* __restrict__ qb) {
  __shared__ float xs[32][128];
  int ty, base, nrows;
  seg_decode(blockIdx.x, ty, base, nrows);
  int t = threadIdx.x;
#pragma unroll
  for (int it = 0; it < 4; ++it) {
    int idx4 = t + it * 256;
    int row = idx4 >> 5, c4 = idx4 & 31;
    float4 val = make_float4(0.f, 0.f, 0.f, 0.f);
    if (row < nrows) val = ((const float4*)(x + (size_t)(base + row) * INF))[c4];
    ((float4*)&xs[row][0])[c4] = val;
  }
  __syncthreads();
  int o = t & 127, g = t >> 7;
  float ak[16], aq[16], av[16];
#pragma unroll
  for (int j = 0; j < 16; ++j) { ak[j] = 0.f; aq[j] = 0.f; av[j] = 0.f; }
  const float* WK = Wk + ty * 16384;
  const float* WQ = Wq + ty * 16384;
  const float* WV = Wv + ty * 16384;
  for (int i0 = 0; i0 < 32; ++i0) {
    float wk[4], wq[4], wv[4];
#pragma unroll
    for (int di = 0; di < 4; ++di) {
      int i = i0 * 4 + di;
      wk[di] = WK[i * 128 + o];
      wq[di] = WQ[i * 128 + o];
      wv[di] = WV[i * 128 + o];
    }
#pragma unroll
    for (int j = 0; j < 16; ++j) {
      float4 x4 = ((const float4*)&xs[g * 16 + j][0])[i0];
      ak[j] += x4.x * wk[0] + x4.y * wk[1] + x4.z * wk[2] + x4.w * wk[3];
      aq[j] += x4.x * wq[0] + x4.y * wq[1] + x4.z * wq[2] + x4.w * wq[3];
      av[j] += x4.x * wv[0] + x4.y * wv[1] + x4.z * wv[2] + x4.w * wv[3];
    }
  }
#pragma unroll
  for (int j = 0; j < 16; ++j) {
    int row = g * 16 + j;
    float akn = __shfl_xor(ak[j], 1);   // neighbor column value (same row)
    float avn = __shfl_xor(av[j], 1);
    if (row < nrows) {
      size_t p = (size_t)(base + row);
      qb[p * INF + o] = aq[j];
      if ((o & 1) == 0)
        kvb[p * 64 + (o >> 1)] = make_uint2(bpack(ak[j], akn), bpack(av[j], avn));
    }
  }
}

// ---- fused attention: logits + edge-softmax + aggregation ---------------
// 1 wave per dst node, 4 nodes per 256-thread block.
// lane l: head h = l>>3, j = l&7 -> dims (h*16+2j, h*16+2j+1).
// Indices for up to 64 edges vector-loaded per wave; kv gathers pipelined
// 1 edge ahead; k/v bf16-packed (one dwordx2 gather per edge).
__global__ __launch_bounds__(256) void k_fused(const uint2* __restrict__ kvb,
                                               const float* __restrict__ qb,
                                               const int* __restrict__ off,
                                               const int* __restrict__ eidx,
                                               const int* __restrict__ src,
                                               const int* __restrict__ etp,
                                               const float* __restrict__ rel_att,
                                               const float* __restrict__ AmT,
                                               const float* __restrict__ pri,
                                               float* __restrict__ hb) {
  __shared__ float qs[4][128];
  __shared__ float accs[4][4][128];
  int w = threadIdx.x >> 6, l = threadIdx.x & 63;
  int n = blockIdx.x * 4 + w;
  int h = l >> 3, j = l & 7;

  // stage q row for this wave's node
  float2 qv = ((const float2*)qb)[(size_t)n * 64 + l];
  ((float2*)&qs[w][0])[l] = qv;
  __syncthreads();

  // qA[ty][2j,2j+1] per lane
  float2 qa0, qa1, qa2, qa3;
#define QA_COMPUTE(QA, TY) { \
    float ax = 0.f, ay = 0.f; \
    const float4* Ar = (const float4*)(rel_att + ((h * 4 + (TY)) * 16) * 16); \
    _Pragma("unroll") \
    for (int d4 = 0; d4 < 4; ++d4) { \
      float4 q4 = *((float4*)&qs[w][h * 16 + d4 * 4]); \
      float4 a0 = Ar[(2 * j) * 4 + d4]; \
      float4 a1 = Ar[(2 * j + 1) * 4 + d4]; \
      ax += a0.x * q4.x + a0.y * q4.y + a0.z * q4.z + a0.w * q4.w; \
      ay += a1.x * q4.x + a1.y * q4.y + a1.z * q4.z + a1.w * q4.w; \
    } \
    QA = make_float2(ax, ay); }
  QA_COMPUTE(qa0, 0)
  QA_COMPUTE(qa1, 1)
  QA_COMPUTE(qa2, 2)
  QA_COMPUTE(qa3, 3)
#undef QA_COMPUTE

  float4 prh = ((const float4*)pri)[h];
  int o0 = off[n], o1 = off[n + 1];
  float m = -INFINITY, ssum = 0.f;
  float2 acc0 = make_float2(0.f, 0.f), acc1 = acc0, acc2 = acc0, acc3 = acc0;

  for (int b0 = o0; b0 < o1; b0 += 64) {
    int cnt = o1 - b0; if (cnt > 64) cnt = 64;
    // vector-load indices for this chunk: lane i holds edge b0+i
    int p = b0 + (l < cnt ? l : cnt - 1);
    int e = eidx[p];
    int st = (src[e] << 2) | etp[e];

    // prefetch edge 0's kv row
    int stc = __shfl(st, 0);
    uint2 kvc = kvb[(size_t)(stc >> 2) * 64 + l];

    for (int i = 0; i < cnt; ++i) {
      // prefetch next edge (redundant re-fetch of last edge on final iter)
      int ii = (i + 1 < cnt) ? (i + 1) : (cnt - 1);
      int stn = __shfl(st, ii);
      uint2 kvn = kvb[(size_t)(stn >> 2) * 64 + l];

      int ty = stc & 3;
      float kx = blo(kvc.x), ky = bhi(kvc.x);
      float2 qat = (ty == 0) ? qa0 : (ty == 1) ? qa1 : (ty == 2) ? qa2 : qa3;
      float part = kx * qat.x + ky * qat.y;
      part += __shfl_xor(part, 1);
      part += __shfl_xor(part, 2);
      part += __shfl_xor(part, 4);
      float pr = (ty == 0) ? prh.x : (ty == 1) ? prh.y : (ty == 2) ? prh.z : prh.w;
      float a = part * pr * 0.25f;
      float mn = fmaxf(m, a);
      float sc = __expf(m - mn);
      float wgt = __expf(a - mn);
      ssum = ssum * sc + wgt;
      float vx = blo(kvc.y), vy = bhi(kvc.y);
      float w0 = (ty == 0) ? wgt : 0.f;
      float w1 = (ty == 1) ? wgt : 0.f;
      float w2 = (ty == 2) ? wgt : 0.f;
      float w3 = (ty == 3) ? wgt : 0.f;
      acc0.x = acc0.x * sc + w0 * vx; acc0.y = acc0.y * sc + w0 * vy;
      acc1.x = acc1.x * sc + w1 * vx; acc1.y = acc1.y * sc + w1 * vy;
      acc2.x = acc2.x * sc + w2 * vx; acc2.y = acc2.y * sc + w2 * vy;
      acc3.x = acc3.x * sc + w3 * vx; acc3.y = acc3.y * sc + w3 * vy;
      m = mn;
      stc = stn; kvc = kvn;
    }
  }

  float inv = (ssum > 0.f) ? 1.f / ssum : 0.f;
  acc0.x *= inv; acc0.y *= inv;
  acc1.x *= inv; acc1.y *= inv;
  acc2.x *= inv; acc2.y *= inv;
  acc3.x *= inv; acc3.y *= inv;

  // stage normalized per-ty accumulators, then apply rel_msg^T once
  ((float2*)&accs[w][0][0])[l] = acc0;
  ((float2*)&accs[w][1][0])[l] = acc1;
  ((float2*)&accs[w][2][0])[l] = acc2;
  ((float2*)&accs[w][3][0])[l] = acc3;

  float ox = 0.f, oy = 0.f;
#pragma unroll
  for (int ty = 0; ty < 4; ++ty) {
    const float4* AmR = (const float4*)(AmT + ((h * 4 + ty) * 16) * 16);
#pragma unroll
    for (int d4 = 0; d4 < 4; ++d4) {
      float4 ac = *((float4*)&accs[w][ty][h * 16 + d4 * 4]);
      float4 m0 = AmR[(2 * j) * 4 + d4];
      float4 m1 = AmR[(2 * j + 1) * 4 + d4];
      ox += m0.x * ac.x + m0.y * ac.y + m0.z * ac.z + m0.w * ac.w;
      oy += m1.x * ac.x + m1.y * ac.y + m1.z * ac.z + m1.w * ac.w;
    }
  }
  ((float2*)hb)[(size_t)n * 64 + l] = make_float2(ox, oy);
}

// ---- typed output projection + sigmoid-skip residual (in-place on x) -----
__global__ __launch_bounds__(256) void k_out(const float* __restrict__ hb,
                                             const float* __restrict__ Wa,
                                             const float* __restrict__ skipv,
                                             float* __restrict__ xio) {
  __shared__ float hs[32][128];
  int ty, base, nrows;
  seg_decode(blockIdx.x, ty, base, nrows);
  int t = threadIdx.x;
#pragma unroll
  for (int it = 0; it < 4; ++it) {
    int idx4 = t + it * 256;
    int row = idx4 >> 5, c4 = idx4 & 31;
    float4 val = make_float4(0.f, 0.f, 0.f, 0.f);
    if (row < nrows) val = ((const float4*)(hb + (size_t)(base + row) * INF))[c4];
    ((float4*)&hs[row][0])[c4] = val;
  }
  __syncthreads();
  int o = t & 127, g = t >> 7;
  float acc[16];
#pragma unroll
  for (int j = 0; j < 16; ++j) acc[j] = 0.f;
  const float* WA = Wa + ty * 16384;
  for (int i0 = 0; i0 < 32; ++i0) {
    float wa[4];
#pragma unroll
    for (int di = 0; di < 4; ++di) wa[di] = WA[(i0 * 4 + di) * 128 + o];
#pragma unroll
    for (int j = 0; j < 16; ++j) {
      float4 h4 = ((const float4*)&hs[g * 16 + j][0])[i0];
      acc[j] += h4.x * wa[0] + h4.y * wa[1] + h4.z * wa[2] + h4.w * wa[3];
    }
  }
  float alpha = 1.f / (1.f + __expf(-skipv[ty]));
  float beta = 1.f - alpha;
#pragma unroll
  for (int j = 0; j < 16; ++j) {
    int row = g * 16 + j;
    if (row < nrows) {
      size_t p = (size_t)(base + row) * INF + o;
      xio[p] = acc[j] * alpha + xio[p] * beta;
    }
  }
}

extern "C" void kernel_launch(void* const* d_in, const int* in_sizes, int n_in,
                              void* d_out, int out_size, void* d_ws, size_t ws_size,
                              hipStream_t stream) {
  const float* drug = (const float*)d_in[0];
  const float* dis  = (const float*)d_in[1];
  const float* prot = (const float*)d_in[2];
  const int* src    = (const int*)d_in[3];
  const int* dst    = (const int*)d_in[4];
  const int* etp    = (const int*)d_in[5];
  const float* Wk   = (const float*)d_in[6];
  const float* Wq   = (const float*)d_in[7];
  const float* Wv   = (const float*)d_in[8];
  const float* Wa   = (const float*)d_in[9];
  const float* rel_att = (const float*)d_in[10];
  const float* rel_msg = (const float*)d_in[11];
  const float* pri  = (const float*)d_in[12];
  const float* skip = (const float*)d_in[13];
  float* x = (float*)d_out;

  char* w = (char*)d_ws;
  uint2* kvb  = (uint2*)(w + 0);            // 25,600,000 B (50000 * 512)
  float* qb   = (float*)(w + 25600000);     // 25,600,000 B
  float* hb   = (float*)(w + 51200000);     // 25,600,000 B
  float* AmT  = (float*)(w + 76800000);     //     32,768 B
  int*   deg  = (int*)(w + 76832768);       //    200,000 B
  int*   off  = (int*)(w + 77032768);       //    200,004 B
  int*   cur  = (int*)(w + 77232772);       //    200,000 B
  int*   eidx = (int*)(w + 77432772);       //  1,600,000 B

  // x = concat(features)
  k_concat<<<6250, 256, 0, stream>>>(drug, dis, prot, x);

  // CSR by dst (edges constant across layers)
  hipMemsetAsync(deg, 0, N_NODE * sizeof(int), stream);
  k_count<<<(N_EDGE + 255) / 256, 256, 0, stream>>>(dst, deg);
  k_scan<<<1, 1024, 0, stream>>>(deg, off, cur);
  k_fill<<<(N_EDGE + 255) / 256, 256, 0, stream>>>(dst, cur, eidx);

  // rel_msg transpose (constant across layers)
  k_trmsg<<<32, 256, 0, stream>>>(rel_msg, AmT);

  for (int layer = 0; layer < 2; ++layer) {
    k_qkv<<<NTILES, 256, 0, stream>>>(x, Wk, Wq, Wv, kvb, qb);
    k_fused<<<12500, 256, 0, stream>>>(kvb, qb, off, eidx, src, etp,
                                       rel_att, AmT, pri, hb);
    k_out<<<NTILES, 256, 0, stream>>>(hb, Wa, skip, x);
  }
}